// Round 1
// baseline (232.730 us; speedup 1.0000x reference)
//
#include <hip/hip_runtime.h>
#include <hip/hip_bf16.h>
#include <stdint.h>

typedef __attribute__((ext_vector_type(8))) short bf16x8;
typedef __attribute__((ext_vector_type(4))) float f32x4;
typedef __attribute__((ext_vector_type(4))) unsigned short u16x4;

#define B_ 4
#define T_ 2048
#define C_ 1024
#define H_ 16
#define D_ 64

// round-to-nearest-even fp32 -> bf16
__device__ __forceinline__ unsigned short f2bf(float f) {
  union { float f; uint32_t u; } v; v.f = f;
  uint32_t u = v.u;
  uint32_t r = (u + 0x7FFFu + ((u >> 16) & 1u)) >> 16;
  return (unsigned short)r;
}

__global__ void __launch_bounds__(256) cast_f32_bf16(const float* __restrict__ src,
                                                     unsigned short* __restrict__ dst,
                                                     int n4) {
  int i = blockIdx.x * 256 + threadIdx.x;
  if (i >= n4) return;
  float4 f = ((const float4*)src)[i];
  u16x4 o;
  o[0] = f2bf(f.x); o[1] = f2bf(f.y); o[2] = f2bf(f.z); o[3] = f2bf(f.w);
  ((u16x4*)dst)[i] = o;
}

// C = A[M,K=1024] * B[N,K=1024]^T, bf16 in, fp32 acc.
// 128x128 block tile, BK=32, 256 threads = 4 waves in 2x2, each wave 64x64 (4x4 mfma tiles).
// LDS row stride 40 shorts (80 B = 5*16B aligned, 20-word bank stride -> 2-way aliasing = free).
// MODE 0: scatter-epilogue to q/k/v [B,H,T,D] bf16.  MODE 1: plain fp32 store.
template <int MODE>
__global__ void __launch_bounds__(256) gemm_bt(const unsigned short* __restrict__ A,
                                               const unsigned short* __restrict__ Bm,
                                               unsigned short* __restrict__ qb,
                                               unsigned short* __restrict__ kb,
                                               unsigned short* __restrict__ vb,
                                               float* __restrict__ fo) {
  __shared__ short As[128 * 40];
  __shared__ short Bs[128 * 40];
  const int tid = threadIdx.x;
  const int bm = blockIdx.y * 128;
  const int bn = blockIdx.x * 128;
  const int wave = tid >> 6;
  const int l = tid & 63;
  const int wm = wave >> 1, wn = wave & 1;
  const int lm = l & 15, lq = l >> 4;
  const int r0 = tid >> 2;          // staging row 0..63 (and +64)
  const int c0 = (tid & 3) << 3;    // staging k-col {0,8,16,24}

  f32x4 acc[4][4];
#pragma unroll
  for (int i = 0; i < 4; i++)
#pragma unroll
    for (int j = 0; j < 4; j++) acc[i][j] = (f32x4){0.f, 0.f, 0.f, 0.f};

  const unsigned short* Ap = A + (size_t)(bm + r0) * 1024 + c0;
  const unsigned short* Bp = Bm + (size_t)(bn + r0) * 1024 + c0;

  for (int k0 = 0; k0 < 1024; k0 += 32) {
    bf16x8 a0 = *(const bf16x8*)(Ap + k0);
    bf16x8 a1 = *(const bf16x8*)(Ap + (size_t)64 * 1024 + k0);
    bf16x8 b0 = *(const bf16x8*)(Bp + k0);
    bf16x8 b1 = *(const bf16x8*)(Bp + (size_t)64 * 1024 + k0);
    __syncthreads();  // previous compute done, LDS free
    *(bf16x8*)&As[r0 * 40 + c0] = a0;
    *(bf16x8*)&As[(r0 + 64) * 40 + c0] = a1;
    *(bf16x8*)&Bs[r0 * 40 + c0] = b0;
    *(bf16x8*)&Bs[(r0 + 64) * 40 + c0] = b1;
    __syncthreads();  // tile ready
    bf16x8 af[4], bfr[4];
#pragma unroll
    for (int i = 0; i < 4; i++)
      af[i] = *(const bf16x8*)&As[(wm * 64 + 16 * i + lm) * 40 + 8 * lq];
#pragma unroll
    for (int j = 0; j < 4; j++)
      bfr[j] = *(const bf16x8*)&Bs[(wn * 64 + 16 * j + lm) * 40 + 8 * lq];
#pragma unroll
    for (int i = 0; i < 4; i++)
#pragma unroll
      for (int j = 0; j < 4; j++)
        acc[i][j] = __builtin_amdgcn_mfma_f32_16x16x32_bf16(af[i], bfr[j], acc[i][j], 0, 0, 0);
  }

  // C/D layout: col = lane&15, row = (lane>>4)*4 + reg  [measured m89/m91]
#pragma unroll
  for (int i = 0; i < 4; i++) {
#pragma unroll
    for (int j = 0; j < 4; j++) {
#pragma unroll
      for (int r = 0; r < 4; r++) {
        int m = bm + wm * 64 + 16 * i + 4 * lq + r;
        int n = bn + wn * 64 + 16 * j + lm;
        float val = acc[i][j][r];
        if (MODE == 0) {
          int which = n >> 10, rem = n & 1023;
          int h = rem >> 6, d = rem & 63;
          int b = m >> 11, t = m & 2047;
          unsigned short* dst = (which == 0) ? qb : ((which == 1) ? kb : vb);
          dst[(((size_t)(b * 16 + h)) * 2048 + t) * 64 + d] = f2bf(val);
        } else {
          fo[(size_t)m * 1024 + n] = val;
        }
      }
    }
  }
}

// Sliding-window causal flash attention.
// One wave per (b,h, 16-query tile); 32-key chunks; online softmax in base 2.
// q/k/v in [B,H,T,D] bf16; output [B,T,H*D] bf16.
__global__ void __launch_bounds__(256) attn_swa(const unsigned short* __restrict__ Qb,
                                               const unsigned short* __restrict__ Kb,
                                               const unsigned short* __restrict__ Vb,
                                               unsigned short* __restrict__ Ob) {
  __shared__ short P[4][16 * 40];  // per-wave P tile, row stride 40 (16B-aligned rows)
  const int wv = threadIdx.x >> 6;
  const int l = threadIdx.x & 63;
  const int wid = blockIdx.x * 4 + wv;
  const int bh = wid >> 7;           // 128 q-tiles per (b,h)
  const int t0 = (wid & 127) << 4;
  const int lm = l & 15, lq = l >> 4;
  const size_t base = (size_t)bh * (T_ * D_);

  // Q A-fragments: A[m=lane&15][k=quad*8+j], two k-halves (d 0..31, 32..63)
  bf16x8 aq0 = *(const bf16x8*)(Qb + base + (size_t)(t0 + lm) * 64 + 8 * lq);
  bf16x8 aq1 = *(const bf16x8*)(Qb + base + (size_t)(t0 + lm) * 64 + 32 + 8 * lq);

  float mst[4], lst[4];
  f32x4 Oa[4];
#pragma unroll
  for (int r = 0; r < 4; r++) { mst[r] = -1e30f; lst[r] = 0.f; }
#pragma unroll
  for (int jt = 0; jt < 4; jt++) Oa[jt] = (f32x4){0.f, 0.f, 0.f, 0.f};

  const float cs = 0.125f * 1.44269504f;  // scale * log2(e)
  int jstart = t0 - 128; if (jstart < 0) jstart = 0;

  for (int j0 = jstart; j0 < t0 + 16; j0 += 32) {
    f32x4 S[2];
#pragma unroll
    for (int hh = 0; hh < 2; hh++) {
      int kr = j0 + 16 * hh + lm; if (kr > T_ - 1) kr = T_ - 1;  // OOB rows are causal-masked
      bf16x8 bk0 = *(const bf16x8*)(Kb + base + (size_t)kr * 64 + 8 * lq);
      bf16x8 bk1 = *(const bf16x8*)(Kb + base + (size_t)kr * 64 + 32 + 8 * lq);
      f32x4 s = (f32x4){0.f, 0.f, 0.f, 0.f};
      s = __builtin_amdgcn_mfma_f32_16x16x32_bf16(aq0, bk0, s, 0, 0, 0);
      s = __builtin_amdgcn_mfma_f32_16x16x32_bf16(aq1, bk1, s, 0, 0, 0);
      S[hh] = s;
    }
    float p0s[4], p1s[4], al[4];
#pragma unroll
    for (int r = 0; r < 4; r++) {
      int t = t0 + 4 * lq + r;
      int ja = j0 + lm, jb = j0 + 16 + lm;
      float s0 = ((ja <= t) && (ja + 128 >= t)) ? S[0][r] * cs : -1e30f;
      float s1 = ((jb <= t) && (jb + 128 >= t)) ? S[1][r] * cs : -1e30f;
      float m2 = fmaxf(s0, s1);
#pragma unroll
      for (int off = 1; off < 16; off <<= 1) m2 = fmaxf(m2, __shfl_xor(m2, off));
      float mn = fmaxf(mst[r], m2);
      float a = __builtin_amdgcn_exp2f(mst[r] - mn);
      float p0 = __builtin_amdgcn_exp2f(s0 - mn);
      float p1 = __builtin_amdgcn_exp2f(s1 - mn);
      float ps = p0 + p1;
#pragma unroll
      for (int off = 1; off < 16; off <<= 1) ps += __shfl_xor(ps, off);
      lst[r] = lst[r] * a + ps;
      mst[r] = mn;
      al[r] = a; p0s[r] = p0; p1s[r] = p1;
    }
#pragma unroll
    for (int jt = 0; jt < 4; jt++)
#pragma unroll
      for (int r = 0; r < 4; r++) Oa[jt][r] *= al[r];
    // P: C-layout -> LDS -> A-layout (per m120); same-wave LDS, no barrier needed
#pragma unroll
    for (int r = 0; r < 4; r++) {
      P[wv][(4 * lq + r) * 40 + lm] = (short)f2bf(p0s[r]);
      P[wv][(4 * lq + r) * 40 + 16 + lm] = (short)f2bf(p1s[r]);
    }
    bf16x8 pa = *(const bf16x8*)&P[wv][lm * 40 + 8 * lq];
#pragma unroll
    for (int jt = 0; jt < 4; jt++) {
      bf16x8 vf;  // B-frag: V[k=quad*8+jj][n=16*jt+lm] (transposed gather, L1-served)
#pragma unroll
      for (int jj = 0; jj < 8; jj++) {
        int kk = j0 + 8 * lq + jj; if (kk > T_ - 1) kk = T_ - 1;
        vf[jj] = (short)Vb[base + (size_t)kk * 64 + 16 * jt + lm];
      }
      Oa[jt] = __builtin_amdgcn_mfma_f32_16x16x32_bf16(pa, vf, Oa[jt], 0, 0, 0);
    }
  }
  const int b = bh >> 4, h = bh & 15;
#pragma unroll
  for (int r = 0; r < 4; r++) {
    float inv = 1.0f / lst[r];
    int t = t0 + 4 * lq + r;
#pragma unroll
    for (int jt = 0; jt < 4; jt++) {
      int c = h * 64 + 16 * jt + lm;
      Ob[((size_t)(b * T_ + t)) * 1024 + c] = f2bf(Oa[jt][r] * inv);
    }
  }
}

extern "C" void kernel_launch(void* const* d_in, const int* in_sizes, int n_in,
                              void* d_out, int out_size, void* d_ws, size_t ws_size,
                              hipStream_t stream) {
  const float* x = (const float*)d_in[0];       // [4,2048,1024]
  const float* w_qkv = (const float*)d_in[1];   // [3072,1024]
  const float* w_out = (const float*)d_in[2];   // [1024,1024]
  float* out = (float*)d_out;                   // [4,2048,1024] fp32

  // workspace layout (bf16 = unsigned short), ~72 MB total
  unsigned short* xb = (unsigned short*)d_ws;                // 8192*1024 (reused as attn out)
  unsigned short* wqkvb = xb + (size_t)8192 * 1024;          // 3072*1024
  unsigned short* woutb = wqkvb + (size_t)3072 * 1024;       // 1024*1024
  unsigned short* qb = woutb + (size_t)1024 * 1024;          // 64*2048*64
  unsigned short* kb = qb + (size_t)64 * 2048 * 64;
  unsigned short* vb = kb + (size_t)64 * 2048 * 64;

  cast_f32_bf16<<<8192, 256, 0, stream>>>(x, xb, 8192 * 1024 / 4);
  cast_f32_bf16<<<3072, 256, 0, stream>>>(w_qkv, wqkvb, 3072 * 1024 / 4);
  cast_f32_bf16<<<1024, 256, 0, stream>>>(w_out, woutb, 1024 * 1024 / 4);

  // qkv = x @ w_qkv^T, scattered to q/k/v [B,H,T,D]
  gemm_bt<0><<<dim3(24, 64), 256, 0, stream>>>(xb, wqkvb, qb, kb, vb, nullptr);

  // sliding-window attention -> [B,T,C] bf16 (aliases xb; xb is dead after gemm_qkv)
  attn_swa<<<2048, 256, 0, stream>>>(qb, kb, vb, xb);

  // out = attn @ w_out^T (fp32 store)
  gemm_bt<1><<<dim3(8, 64), 256, 0, stream>>>(xb, woutb, nullptr, nullptr, nullptr, out);
}